// Round 1
// baseline (245.337 us; speedup 1.0000x reference)
//
#include <hip/hip_runtime.h>
#include <hip/hip_bf16.h>
#include <stdint.h>

#define M_ROWS 8192
#define K_DIM  1024
#define N_COLS 4096

typedef short bf16x8 __attribute__((ext_vector_type(8)));
typedef float f32x4  __attribute__((ext_vector_type(4)));

__device__ __forceinline__ unsigned short f2bf(float f) {
  unsigned int u = __float_as_uint(f);
  unsigned int r = (u + 0x7FFFu + ((u >> 16) & 1u)) >> 16;
  return (unsigned short)r;
}

// ---------------- routing: cluster-active 64-bit mask ----------------
// lane == cluster. Each wave owns 4 rows. Centroid chunks staged transposed
// in LDS (stride 65 -> conflict-free reads, lane c reads ct[d*65+c]).
__global__ __launch_bounds__(256) void routing_kernel(
    const float* __restrict__ x, const float* __restrict__ cent,
    unsigned long long* __restrict__ mask) {
  __shared__ float ct[128 * 65];  // 33.25 KB
  const int t = threadIdx.x;
  const int l = t & 63;
  const int w = __builtin_amdgcn_readfirstlane(t >> 6);
  const int row0 = blockIdx.x * 16 + w * 4;

  float acc[4] = {0.f, 0.f, 0.f, 0.f};

  for (int dc = 0; dc < 8; ++dc) {  // 8 chunks of 128 dims
    __syncthreads();
    #pragma unroll
    for (int rep = 0; rep < 32; ++rep) {
      int flat = rep * 256 + t;          // 0..8191 = 64c x 128d
      int c = flat >> 7, d = flat & 127;
      ct[d * 65 + c] = cent[c * K_DIM + dc * 128 + d];
    }
    __syncthreads();
    for (int d4 = 0; d4 < 32; ++d4) {
      float xv[4][4];
      #pragma unroll
      for (int r = 0; r < 4; ++r) {
        const float4 v = *(const float4*)&x[(size_t)(row0 + r) * K_DIM + dc * 128 + d4 * 4];
        xv[r][0] = v.x; xv[r][1] = v.y; xv[r][2] = v.z; xv[r][3] = v.w;
      }
      #pragma unroll
      for (int dd = 0; dd < 4; ++dd) {
        const float cv = ct[(d4 * 4 + dd) * 65 + l];
        #pragma unroll
        for (int r = 0; r < 4; ++r) acc[r] = fmaf(xv[r][dd], cv, acc[r]);
      }
    }
  }

  // per-row softmax threshold; reduce across the 64 lanes (=clusters)
  bool flag = false;
  #pragma unroll
  for (int r = 0; r < 4; ++r) {
    float m = acc[r];
    #pragma unroll
    for (int off = 32; off >= 1; off >>= 1) m = fmaxf(m, __shfl_xor(m, off));
    const float e = expf(acc[r] - m);
    float se = e;
    #pragma unroll
    for (int off = 32; off >= 1; off >>= 1) se += __shfl_xor(se, off);
    if (e > 1e-4f * se) flag = true;
  }
  const unsigned long long b = __ballot(flag);
  if (l == 0) atomicOr(mask, b);
}

// ---------------- fp32 -> bf16 conversion (x then W) ----------------
__global__ __launch_bounds__(256) void convert_kernel(
    const float* __restrict__ x, const float* __restrict__ wgt,
    unsigned short* __restrict__ xb, unsigned short* __restrict__ wb) {
  const size_t g = (size_t)blockIdx.x * 256 + threadIdx.x;
  const size_t NXG = (size_t)M_ROWS * K_DIM / 4;  // 2097152 float4 groups of x
  const float* src; unsigned short* dst; size_t gg;
  if (g < NXG) { src = x;   dst = xb; gg = g; }
  else         { src = wgt; dst = wb; gg = g - NXG; }
  const float4 v = *(const float4*)&src[gg * 4];
  ushort4 o;
  o.x = f2bf(v.x); o.y = f2bf(v.y); o.z = f2bf(v.z); o.w = f2bf(v.w);
  *(ushort4*)&dst[gg * 4] = o;
}

// ---------------- bf16 MFMA GEMM, m97 structure, fused mask+bias ----------------
// out[m][n] = sum_k x[m][k]*W[n][k] (+bias) if cluster_active[assign[n]] else 0
__global__ __launch_bounds__(256) void gemm_kernel(
    const unsigned short* __restrict__ xb, const unsigned short* __restrict__ wb,
    const float* __restrict__ bias, const int* __restrict__ assign,
    const unsigned long long* __restrict__ maskp,
    float* __restrict__ out) {
  __shared__ unsigned short Al[128 * 32];  // 8 KB, row-major [m][k]
  __shared__ unsigned short Bl[128 * 32];  // 8 KB, row-major [n][k]

  const int t = threadIdx.x;
  const int l = t & 63;
  const int w = t >> 6;
  const int wm = w >> 1, wn = w & 1;
  const int lr = l & 15;          // fragment row/col index
  const int lk = (l >> 4) * 8;    // fragment k offset (elements)

  // XCD-bijective swizzle: 2048 blocks, %8 == 0
  const int nwg = gridDim.x;
  const int cpx = nwg >> 3;
  const int bid = blockIdx.x;
  const int swz = (bid & 7) * cpx + (bid >> 3);
  const int TN = N_COLS / 128;    // 32
  const int bm = swz / TN, bn = swz % TN;
  const int m0 = bm * 128, n0 = bn * 128;

  f32x4 acc[4][4];
  #pragma unroll
  for (int i = 0; i < 4; ++i)
    #pragma unroll
    for (int j = 0; j < 4; ++j) acc[i][j] = {0.f, 0.f, 0.f, 0.f};

  for (int kt = 0; kt < K_DIM / 32; ++kt) {
    // stage 8KB A-tile + 8KB B-tile; 16B per lane; LDS dest linear (wave base + lane*16)
    #pragma unroll
    for (int it = 0; it < 2; ++it) {
      const int tt = it * 256 + t;
      const int row = tt >> 2;
      const int kc = (tt & 3) * 8;
      const unsigned short* ga = xb + (size_t)(m0 + row) * K_DIM + kt * 32 + kc;
      const unsigned short* gb = wb + (size_t)(n0 + row) * K_DIM + kt * 32 + kc;
      char* la = (char*)Al + it * 4096 + (t & 192) * 16;  // wave-uniform base
      char* lb = (char*)Bl + it * 4096 + (t & 192) * 16;
      __builtin_amdgcn_global_load_lds((const __attribute__((address_space(1))) void*)ga,
                                       (__attribute__((address_space(3))) void*)la, 16, 0, 0);
      __builtin_amdgcn_global_load_lds((const __attribute__((address_space(1))) void*)gb,
                                       (__attribute__((address_space(3))) void*)lb, 16, 0, 0);
    }
    __syncthreads();  // compiler emits vmcnt(0) drain before barrier

    bf16x8 af[4], bfr[4];
    #pragma unroll
    for (int mi = 0; mi < 4; ++mi)
      af[mi] = *(const bf16x8*)&Al[(wm * 64 + mi * 16 + lr) * 32 + lk];
    #pragma unroll
    for (int ni = 0; ni < 4; ++ni)
      bfr[ni] = *(const bf16x8*)&Bl[(wn * 64 + ni * 16 + lr) * 32 + lk];
    #pragma unroll
    for (int mi = 0; mi < 4; ++mi)
      #pragma unroll
      for (int ni = 0; ni < 4; ++ni)
        acc[mi][ni] = __builtin_amdgcn_mfma_f32_16x16x32_bf16(af[mi], bfr[ni], acc[mi][ni], 0, 0, 0);
    __syncthreads();  // all waves done reading before next stage overwrites
  }

  // epilogue: C/D layout col=l&15, row=(l>>4)*4+j  [m89-verified]
  const unsigned long long mask = *maskp;
  #pragma unroll
  for (int ni = 0; ni < 4; ++ni) {
    const int col = n0 + wn * 64 + ni * 16 + lr;
    const int a = assign[col];
    const bool act = (mask >> a) & 1ull;
    const float bv = bias[col];
    #pragma unroll
    for (int mi = 0; mi < 4; ++mi) {
      #pragma unroll
      for (int j = 0; j < 4; ++j) {
        const int row = m0 + wm * 64 + mi * 16 + (l >> 4) * 4 + j;
        out[(size_t)row * N_COLS + col] = act ? (acc[mi][ni][j] + bv) : 0.0f;
      }
    }
  }
}

extern "C" void kernel_launch(void* const* d_in, const int* in_sizes, int n_in,
                              void* d_out, int out_size, void* d_ws, size_t ws_size,
                              hipStream_t stream) {
  const float* x    = (const float*)d_in[0];
  const float* wgt  = (const float*)d_in[1];
  const float* bias = (const float*)d_in[2];
  const float* cent = (const float*)d_in[3];
  const int* assign = (const int*)d_in[4];
  float* out = (float*)d_out;

  unsigned long long* mask = (unsigned long long*)d_ws;
  unsigned short* xb = (unsigned short*)((char*)d_ws + 256);
  unsigned short* wb = xb + (size_t)M_ROWS * K_DIM;   // +16 MB

  hipMemsetAsync(d_ws, 0, 8, stream);
  hipLaunchKernelGGL(routing_kernel, dim3(512), dim3(256), 0, stream, x, cent, mask);
  hipLaunchKernelGGL(convert_kernel, dim3((M_ROWS * K_DIM + N_COLS * K_DIM) / 4 / 256), dim3(256),
                     0, stream, x, wgt, xb, wb);
  hipLaunchKernelGGL(gemm_kernel, dim3((M_ROWS / 128) * (N_COLS / 128)), dim3(256), 0, stream,
                     xb, wb, bias, assign, mask, out);
}

// Round 2
// 142.159 us; speedup vs baseline: 1.7258x; 1.7258x over previous
//
#include <hip/hip_runtime.h>
#include <hip/hip_bf16.h>
#include <stdint.h>

#define M_ROWS 8192
#define K_DIM  1024
#define N_COLS 4096
#define N_CLUS 64

typedef short bf16x8 __attribute__((ext_vector_type(8)));
typedef float f32x4  __attribute__((ext_vector_type(4)));

__device__ __forceinline__ unsigned short f2bf(float f) {
  unsigned int u = __float_as_uint(f);
  unsigned int r = (u + 0x7FFFu + ((u >> 16) & 1u)) >> 16;
  return (unsigned short)r;
}

// ---------------- fp32 -> bf16 conversion (x, W, centroids) ----------------
__global__ __launch_bounds__(256) void convert_kernel(
    const float* __restrict__ x, const float* __restrict__ wgt,
    const float* __restrict__ cent,
    unsigned short* __restrict__ xb, unsigned short* __restrict__ wb,
    unsigned short* __restrict__ cb) {
  const size_t g = (size_t)blockIdx.x * 256 + threadIdx.x;
  const size_t NXG = (size_t)M_ROWS * K_DIM / 4;   // x float4 groups
  const size_t NWG = (size_t)N_COLS * K_DIM / 4;   // W float4 groups
  const float* src; unsigned short* dst; size_t gg;
  if (g < NXG)            { src = x;    dst = xb; gg = g; }
  else if (g < NXG + NWG) { src = wgt;  dst = wb; gg = g - NXG; }
  else                    { src = cent; dst = cb; gg = g - NXG - NWG; }
  const float4 v = *(const float4*)&src[gg * 4];
  ushort4 o;
  o.x = f2bf(v.x); o.y = f2bf(v.y); o.z = f2bf(v.z); o.w = f2bf(v.w);
  *(ushort4*)&dst[gg * 4] = o;
}

// ---------------- routing via MFMA: cluster-active 64-bit mask ----------------
// logits = x @ C^T  (M=8192, N=64, K=1024), bf16 MFMA, fp32 accumulate.
// One wave per block, 64 rows per wave. Per-row softmax-threshold reduced
// across the 16-lane column group; ballot -> fold -> one atomicOr per block.
__global__ __launch_bounds__(64) void routing_mfma_kernel(
    const unsigned short* __restrict__ xb, const unsigned short* __restrict__ cb,
    unsigned long long* __restrict__ mask) {
  __shared__ unsigned short Xl[64 * 32];  // 4 KB
  __shared__ unsigned short Cl[64 * 32];  // 4 KB
  const int t = threadIdx.x;              // 0..63, one wave
  const int lr = t & 15;
  const int lk = (t >> 4) * 8;
  const int row0 = blockIdx.x * 64;

  f32x4 acc[4][4];
  #pragma unroll
  for (int i = 0; i < 4; ++i)
    #pragma unroll
    for (int j = 0; j < 4; ++j) acc[i][j] = {0.f, 0.f, 0.f, 0.f};

  for (int kt = 0; kt < K_DIM / 32; ++kt) {
    #pragma unroll
    for (int it = 0; it < 4; ++it) {
      const int tt = it * 64 + t;         // 0..255
      const int row = tt >> 2;
      const int kc = (tt & 3) * 8;
      const unsigned short* gx = xb + (size_t)(row0 + row) * K_DIM + kt * 32 + kc;
      const unsigned short* gc = cb + (size_t)row * K_DIM + kt * 32 + kc;
      char* lx = (char*)Xl + it * 1024;   // wave-uniform base + lane*16 (linear)
      char* lc = (char*)Cl + it * 1024;
      __builtin_amdgcn_global_load_lds((const __attribute__((address_space(1))) void*)gx,
                                       (__attribute__((address_space(3))) void*)lx, 16, 0, 0);
      __builtin_amdgcn_global_load_lds((const __attribute__((address_space(1))) void*)gc,
                                       (__attribute__((address_space(3))) void*)lc, 16, 0, 0);
    }
    __syncthreads();  // vmcnt(0) drain

    bf16x8 af[4], cf[4];
    #pragma unroll
    for (int mi = 0; mi < 4; ++mi)
      af[mi] = *(const bf16x8*)&Xl[(mi * 16 + lr) * 32 + lk];
    #pragma unroll
    for (int ni = 0; ni < 4; ++ni)
      cf[ni] = *(const bf16x8*)&Cl[(ni * 16 + lr) * 32 + lk];
    #pragma unroll
    for (int mi = 0; mi < 4; ++mi)
      #pragma unroll
      for (int ni = 0; ni < 4; ++ni)
        acc[mi][ni] = __builtin_amdgcn_mfma_f32_16x16x32_bf16(af[mi], cf[ni], acc[mi][ni], 0, 0, 0);
    __syncthreads();
  }

  // Per-row (64 clusters) softmax threshold. Row r = mi*16 + (t>>4)*4 + j,
  // this lane holds cols {ni*16+lr}. Reduce over lr (16-lane groups).
  bool colflag[4] = {false, false, false, false};
  #pragma unroll
  for (int mi = 0; mi < 4; ++mi) {
    #pragma unroll
    for (int j = 0; j < 4; ++j) {
      const float v0 = acc[mi][0][j], v1 = acc[mi][1][j],
                  v2 = acc[mi][2][j], v3 = acc[mi][3][j];
      float m = fmaxf(fmaxf(v0, v1), fmaxf(v2, v3));
      #pragma unroll
      for (int off = 8; off >= 1; off >>= 1) m = fmaxf(m, __shfl_xor(m, off));
      float S = expf(v0 - m) + expf(v1 - m) + expf(v2 - m) + expf(v3 - m);
      #pragma unroll
      for (int off = 8; off >= 1; off >>= 1) S += __shfl_xor(S, off);
      const float thr = logf(1e-4f * S);  // e^(v-m) > 1e-4*S  <=>  v-m > thr
      colflag[0] |= (v0 - m) > thr;
      colflag[1] |= (v1 - m) > thr;
      colflag[2] |= (v2 - m) > thr;
      colflag[3] |= (v3 - m) > thr;
    }
  }
  unsigned long long bits = 0;
  #pragma unroll
  for (int ni = 0; ni < 4; ++ni) {
    unsigned long long u = __ballot(colflag[ni]);
    u |= u >> 32; u |= u >> 16;           // fold 4 row-groups onto cols 0..15
    bits |= (u & 0xFFFFull) << (ni * 16);
  }
  if (t == 0) atomicOr(mask, bits);
}

// ---------------- bf16 MFMA GEMM, m97 structure, fused mask+bias ----------------
// out[m][n] = sum_k x[m][k]*W[n][k] (+bias) if cluster_active[assign[n]] else 0
__global__ __launch_bounds__(256) void gemm_kernel(
    const unsigned short* __restrict__ xb, const unsigned short* __restrict__ wb,
    const float* __restrict__ bias, const int* __restrict__ assign,
    const unsigned long long* __restrict__ maskp,
    float* __restrict__ out) {
  __shared__ unsigned short Al[128 * 32];  // 8 KB, row-major [m][k]
  __shared__ unsigned short Bl[128 * 32];  // 8 KB, row-major [n][k]

  const int t = threadIdx.x;
  const int l = t & 63;
  const int w = t >> 6;
  const int wm = w >> 1, wn = w & 1;
  const int lr = l & 15;
  const int lk = (l >> 4) * 8;

  const int nwg = gridDim.x;
  const int cpx = nwg >> 3;
  const int bid = blockIdx.x;
  const int swz = (bid & 7) * cpx + (bid >> 3);
  const int TN = N_COLS / 128;
  const int bm = swz / TN, bn = swz % TN;
  const int m0 = bm * 128, n0 = bn * 128;

  f32x4 acc[4][4];
  #pragma unroll
  for (int i = 0; i < 4; ++i)
    #pragma unroll
    for (int j = 0; j < 4; ++j) acc[i][j] = {0.f, 0.f, 0.f, 0.f};

  for (int kt = 0; kt < K_DIM / 32; ++kt) {
    #pragma unroll
    for (int it = 0; it < 2; ++it) {
      const int tt = it * 256 + t;
      const int row = tt >> 2;
      const int kc = (tt & 3) * 8;
      const unsigned short* ga = xb + (size_t)(m0 + row) * K_DIM + kt * 32 + kc;
      const unsigned short* gb = wb + (size_t)(n0 + row) * K_DIM + kt * 32 + kc;
      char* la = (char*)Al + it * 4096 + (t & 192) * 16;
      char* lb = (char*)Bl + it * 4096 + (t & 192) * 16;
      __builtin_amdgcn_global_load_lds((const __attribute__((address_space(1))) void*)ga,
                                       (__attribute__((address_space(3))) void*)la, 16, 0, 0);
      __builtin_amdgcn_global_load_lds((const __attribute__((address_space(1))) void*)gb,
                                       (__attribute__((address_space(3))) void*)lb, 16, 0, 0);
    }
    __syncthreads();

    bf16x8 af[4], bfr[4];
    #pragma unroll
    for (int mi = 0; mi < 4; ++mi)
      af[mi] = *(const bf16x8*)&Al[(wm * 64 + mi * 16 + lr) * 32 + lk];
    #pragma unroll
    for (int ni = 0; ni < 4; ++ni)
      bfr[ni] = *(const bf16x8*)&Bl[(wn * 64 + ni * 16 + lr) * 32 + lk];
    #pragma unroll
    for (int mi = 0; mi < 4; ++mi)
      #pragma unroll
      for (int ni = 0; ni < 4; ++ni)
        acc[mi][ni] = __builtin_amdgcn_mfma_f32_16x16x32_bf16(af[mi], bfr[ni], acc[mi][ni], 0, 0, 0);
    __syncthreads();
  }

  const unsigned long long mask = *maskp;
  #pragma unroll
  for (int ni = 0; ni < 4; ++ni) {
    const int col = n0 + wn * 64 + ni * 16 + lr;
    const int a = assign[col];
    const bool act = (mask >> a) & 1ull;
    const float bv = bias[col];
    #pragma unroll
    for (int mi = 0; mi < 4; ++mi) {
      #pragma unroll
      for (int j = 0; j < 4; ++j) {
        const int row = m0 + wm * 64 + mi * 16 + (l >> 4) * 4 + j;
        out[(size_t)row * N_COLS + col] = act ? (acc[mi][ni][j] + bv) : 0.0f;
      }
    }
  }
}

extern "C" void kernel_launch(void* const* d_in, const int* in_sizes, int n_in,
                              void* d_out, int out_size, void* d_ws, size_t ws_size,
                              hipStream_t stream) {
  const float* x    = (const float*)d_in[0];
  const float* wgt  = (const float*)d_in[1];
  const float* bias = (const float*)d_in[2];
  const float* cent = (const float*)d_in[3];
  const int* assign = (const int*)d_in[4];
  float* out = (float*)d_out;

  unsigned long long* mask = (unsigned long long*)d_ws;
  unsigned short* xb = (unsigned short*)((char*)d_ws + 256);
  unsigned short* wb = xb + (size_t)M_ROWS * K_DIM;   // +16 MB
  unsigned short* cb = wb + (size_t)N_COLS * K_DIM;   // +8 MB  (cb: 128 KB)

  hipMemsetAsync(d_ws, 0, 8, stream);
  const int ngroups = (M_ROWS * K_DIM + N_COLS * K_DIM + N_CLUS * K_DIM) / 4;
  hipLaunchKernelGGL(convert_kernel, dim3(ngroups / 256), dim3(256), 0, stream,
                     x, wgt, cent, xb, wb, cb);
  hipLaunchKernelGGL(routing_mfma_kernel, dim3(M_ROWS / 64), dim3(64), 0, stream,
                     xb, cb, mask);
  hipLaunchKernelGGL(gemm_kernel, dim3((M_ROWS / 128) * (N_COLS / 128)), dim3(256), 0, stream,
                     xb, wb, bias, assign, mask, out);
}

// Round 3
// 141.779 us; speedup vs baseline: 1.7304x; 1.0027x over previous
//
#include <hip/hip_runtime.h>
#include <hip/hip_bf16.h>
#include <stdint.h>

#define M_ROWS 8192
#define K_DIM  1024
#define N_COLS 4096
#define N_CLUS 64
#define NT     (K_DIM / 32)   // 32 K-steps

typedef short bf16x8 __attribute__((ext_vector_type(8)));
typedef float f32x4  __attribute__((ext_vector_type(4)));

__device__ __forceinline__ unsigned short f2bf(float f) {
  unsigned int u = __float_as_uint(f);
  unsigned int r = (u + 0x7FFFu + ((u >> 16) & 1u)) >> 16;
  return (unsigned short)r;
}

// ---------------- fp32 -> bf16 conversion (x, W, centroids) ----------------
__global__ __launch_bounds__(256) void convert_kernel(
    const float* __restrict__ x, const float* __restrict__ wgt,
    const float* __restrict__ cent,
    unsigned short* __restrict__ xb, unsigned short* __restrict__ wb,
    unsigned short* __restrict__ cb) {
  const size_t g = (size_t)blockIdx.x * 256 + threadIdx.x;
  const size_t NXG = (size_t)M_ROWS * K_DIM / 4;
  const size_t NWG = (size_t)N_COLS * K_DIM / 4;
  const float* src; unsigned short* dst; size_t gg;
  if (g < NXG)            { src = x;    dst = xb; gg = g; }
  else if (g < NXG + NWG) { src = wgt;  dst = wb; gg = g - NXG; }
  else                    { src = cent; dst = cb; gg = g - NXG - NWG; }
  const float4 v = *(const float4*)&src[gg * 4];
  ushort4 o;
  o.x = f2bf(v.x); o.y = f2bf(v.y); o.z = f2bf(v.z); o.w = f2bf(v.w);
  *(ushort4*)&dst[gg * 4] = o;
}

// ---------------- routing via MFMA: cluster-active 64-bit mask ----------------
__global__ __launch_bounds__(64) void routing_mfma_kernel(
    const unsigned short* __restrict__ xb, const unsigned short* __restrict__ cb,
    unsigned long long* __restrict__ mask) {
  __shared__ unsigned short Xl[64 * 32];
  __shared__ unsigned short Cl[64 * 32];
  const int t = threadIdx.x;
  const int lr = t & 15;
  const int lk = (t >> 4) * 8;
  const int row0 = blockIdx.x * 64;

  f32x4 acc[4][4];
  #pragma unroll
  for (int i = 0; i < 4; ++i)
    #pragma unroll
    for (int j = 0; j < 4; ++j) acc[i][j] = {0.f, 0.f, 0.f, 0.f};

  for (int kt = 0; kt < NT; ++kt) {
    #pragma unroll
    for (int it = 0; it < 4; ++it) {
      const int tt = it * 64 + t;
      const int row = tt >> 2;
      const int kc = (tt & 3) * 8;
      const unsigned short* gx = xb + (size_t)(row0 + row) * K_DIM + kt * 32 + kc;
      const unsigned short* gc = cb + (size_t)row * K_DIM + kt * 32 + kc;
      char* lx = (char*)Xl + it * 1024;
      char* lc = (char*)Cl + it * 1024;
      __builtin_amdgcn_global_load_lds((const __attribute__((address_space(1))) void*)gx,
                                       (__attribute__((address_space(3))) void*)lx, 16, 0, 0);
      __builtin_amdgcn_global_load_lds((const __attribute__((address_space(1))) void*)gc,
                                       (__attribute__((address_space(3))) void*)lc, 16, 0, 0);
    }
    __syncthreads();

    bf16x8 af[4], cf[4];
    #pragma unroll
    for (int mi = 0; mi < 4; ++mi)
      af[mi] = *(const bf16x8*)&Xl[(mi * 16 + lr) * 32 + lk];
    #pragma unroll
    for (int ni = 0; ni < 4; ++ni)
      cf[ni] = *(const bf16x8*)&Cl[(ni * 16 + lr) * 32 + lk];
    #pragma unroll
    for (int mi = 0; mi < 4; ++mi)
      #pragma unroll
      for (int ni = 0; ni < 4; ++ni)
        acc[mi][ni] = __builtin_amdgcn_mfma_f32_16x16x32_bf16(af[mi], cf[ni], acc[mi][ni], 0, 0, 0);
    __syncthreads();
  }

  bool colflag[4] = {false, false, false, false};
  #pragma unroll
  for (int mi = 0; mi < 4; ++mi) {
    #pragma unroll
    for (int j = 0; j < 4; ++j) {
      const float v0 = acc[mi][0][j], v1 = acc[mi][1][j],
                  v2 = acc[mi][2][j], v3 = acc[mi][3][j];
      float m = fmaxf(fmaxf(v0, v1), fmaxf(v2, v3));
      #pragma unroll
      for (int off = 8; off >= 1; off >>= 1) m = fmaxf(m, __shfl_xor(m, off));
      float S = expf(v0 - m) + expf(v1 - m) + expf(v2 - m) + expf(v3 - m);
      #pragma unroll
      for (int off = 8; off >= 1; off >>= 1) S += __shfl_xor(S, off);
      const float thr = logf(1e-4f * S);
      colflag[0] |= (v0 - m) > thr;
      colflag[1] |= (v1 - m) > thr;
      colflag[2] |= (v2 - m) > thr;
      colflag[3] |= (v3 - m) > thr;
    }
  }
  unsigned long long bits = 0;
  #pragma unroll
  for (int ni = 0; ni < 4; ++ni) {
    unsigned long long u = __ballot(colflag[ni]);
    u |= u >> 32; u |= u >> 16;
    bits |= (u & 0xFFFFull) << (ni * 16);
  }
  if (t == 0) atomicOr(mask, bits);
}

// ---------------- bf16 MFMA GEMM: 3-buffer counted-vmcnt pipeline ----------------
// out[m][n] = sum_k x[m][k]*W[n][k] (+bias) if cluster_active[assign[n]] else 0
__global__ __launch_bounds__(256) void gemm_kernel(
    const unsigned short* __restrict__ xb, const unsigned short* __restrict__ wb,
    const float* __restrict__ bias, const int* __restrict__ assign,
    const unsigned long long* __restrict__ maskp,
    float* __restrict__ out) {
  // 3 circular tile buffers per operand; 8 KB each half -> 48 KB total
  __shared__ unsigned short Al[3][128 * 32];
  __shared__ unsigned short Bl[3][128 * 32];

  const int t = threadIdx.x;
  const int l = t & 63;
  const int w = t >> 6;
  const int wm = w >> 1, wn = w & 1;
  const int lr = l & 15;
  const int hi = l >> 4;          // chunk selector for swizzled reads

  const int nwg = gridDim.x;
  const int cpx = nwg >> 3;
  const int bid = blockIdx.x;
  const int swz = (bid & 7) * cpx + (bid >> 3);
  const int TN = N_COLS / 128;
  const int bm = swz / TN, bn = swz % TN;
  const int m0 = bm * 128, n0 = bn * 128;

  // stage tile kt into buffer buf. Both-sides swizzle: LDS dest stays linear
  // (gload_lds requirement); global source column is chunk-XOR-permuted so
  // LDS holds element (row, c) at position (row, c ^ ((row&3)*8)).
  auto STAGE = [&](int buf, int kt) {
    #pragma unroll
    for (int it = 0; it < 2; ++it) {
      const int tt = it * 256 + t;
      const int row = tt >> 2;
      const int kc = (((tt & 3) ^ (row & 3)) << 3);   // swizzled source chunk
      const unsigned short* ga = xb + (size_t)(m0 + row) * K_DIM + kt * 32 + kc;
      const unsigned short* gb = wb + (size_t)(n0 + row) * K_DIM + kt * 32 + kc;
      char* la = (char*)&Al[buf][0] + it * 4096 + (t & 192) * 16;  // wave-uniform base
      char* lb = (char*)&Bl[buf][0] + it * 4096 + (t & 192) * 16;
      __builtin_amdgcn_global_load_lds((const __attribute__((address_space(1))) void*)ga,
                                       (__attribute__((address_space(3))) void*)la, 16, 0, 0);
      __builtin_amdgcn_global_load_lds((const __attribute__((address_space(1))) void*)gb,
                                       (__attribute__((address_space(3))) void*)lb, 16, 0, 0);
    }
  };

  f32x4 acc[4][4];
  #pragma unroll
  for (int i = 0; i < 4; ++i)
    #pragma unroll
    for (int j = 0; j < 4; ++j) acc[i][j] = {0.f, 0.f, 0.f, 0.f};

  STAGE(0, 0);
  STAGE(1, 1);

  int bsel = 0;
  for (int kt = 0; kt < NT; ++kt) {
    // tile kt landed; tile kt+1's 4 loads may stay in flight (never drain to 0
    // in the main loop). Raw s_barrier via asm: no compiler vmcnt(0) drain.
    if (kt < NT - 1) asm volatile("s_waitcnt vmcnt(4)" ::: "memory");
    else             asm volatile("s_waitcnt vmcnt(0)" ::: "memory");
    asm volatile("s_barrier" ::: "memory");

    // overwrite the buffer last read at iteration kt-1: safe, those ds_reads
    // completed (lgkmcnt) before their MFMAs, hence before this barrier.
    if (kt + 2 < NT) {
      int nb = bsel + 2; if (nb >= 3) nb -= 3;
      STAGE(nb, kt + 2);
    }

    const unsigned short* Ab = &Al[bsel][0];
    const unsigned short* Bb = &Bl[bsel][0];
    bf16x8 af[4], bfr[4];
    #pragma unroll
    for (int mi = 0; mi < 4; ++mi) {
      const int row = wm * 64 + mi * 16 + lr;
      af[mi] = *(const bf16x8*)&Ab[row * 32 + ((hi ^ (row & 3)) << 3)];
    }
    #pragma unroll
    for (int ni = 0; ni < 4; ++ni) {
      const int row = wn * 64 + ni * 16 + lr;
      bfr[ni] = *(const bf16x8*)&Bb[row * 32 + ((hi ^ (row & 3)) << 3)];
    }
    __builtin_amdgcn_s_setprio(1);
    #pragma unroll
    for (int mi = 0; mi < 4; ++mi)
      #pragma unroll
      for (int ni = 0; ni < 4; ++ni)
        acc[mi][ni] = __builtin_amdgcn_mfma_f32_16x16x32_bf16(af[mi], bfr[ni], acc[mi][ni], 0, 0, 0);
    __builtin_amdgcn_s_setprio(0);

    bsel = (bsel == 2) ? 0 : bsel + 1;
  }

  // epilogue: C/D layout col=l&15, row=(l>>4)*4+j  [m89-verified]
  const unsigned long long mask = *maskp;
  #pragma unroll
  for (int ni = 0; ni < 4; ++ni) {
    const int col = n0 + wn * 64 + ni * 16 + lr;
    const int a = assign[col];
    const bool act = (mask >> a) & 1ull;
    const float bv = bias[col];
    #pragma unroll
    for (int mi = 0; mi < 4; ++mi) {
      #pragma unroll
      for (int j = 0; j < 4; ++j) {
        const int row = m0 + wm * 64 + mi * 16 + hi * 4 + j;
        out[(size_t)row * N_COLS + col] = act ? (acc[mi][ni][j] + bv) : 0.0f;
      }
    }
  }
}

extern "C" void kernel_launch(void* const* d_in, const int* in_sizes, int n_in,
                              void* d_out, int out_size, void* d_ws, size_t ws_size,
                              hipStream_t stream) {
  const float* x    = (const float*)d_in[0];
  const float* wgt  = (const float*)d_in[1];
  const float* bias = (const float*)d_in[2];
  const float* cent = (const float*)d_in[3];
  const int* assign = (const int*)d_in[4];
  float* out = (float*)d_out;

  unsigned long long* mask = (unsigned long long*)d_ws;
  unsigned short* xb = (unsigned short*)((char*)d_ws + 256);
  unsigned short* wb = xb + (size_t)M_ROWS * K_DIM;
  unsigned short* cb = wb + (size_t)N_COLS * K_DIM;

  hipMemsetAsync(d_ws, 0, 8, stream);
  const int ngroups = (M_ROWS * K_DIM + N_COLS * K_DIM + N_CLUS * K_DIM) / 4;
  hipLaunchKernelGGL(convert_kernel, dim3(ngroups / 256), dim3(256), 0, stream,
                     x, wgt, cent, xb, wb, cb);
  hipLaunchKernelGGL(routing_mfma_kernel, dim3(M_ROWS / 64), dim3(64), 0, stream,
                     xb, cb, mask);
  hipLaunchKernelGGL(gemm_kernel, dim3((M_ROWS / 128) * (N_COLS / 128)), dim3(256), 0, stream,
                     xb, wb, bias, assign, mask, out);
}

// Round 4
// 117.501 us; speedup vs baseline: 2.0880x; 1.2066x over previous
//
#include <hip/hip_runtime.h>
#include <hip/hip_bf16.h>
#include <stdint.h>

#define M_ROWS 8192
#define K_DIM  1024
#define N_COLS 4096
#define N_CLUS 64

typedef short bf16x8 __attribute__((ext_vector_type(8)));
typedef float f32x4  __attribute__((ext_vector_type(4)));

__device__ __forceinline__ unsigned short f2bf(float f) {
  unsigned int u = __float_as_uint(f);
  unsigned int r = (u + 0x7FFFu + ((u >> 16) & 1u)) >> 16;
  return (unsigned short)r;
}

// ---------------- fp32 -> bf16 conversion (x, W, centroids) ----------------
__global__ __launch_bounds__(256) void convert_kernel(
    const float* __restrict__ x, const float* __restrict__ wgt,
    const float* __restrict__ cent,
    unsigned short* __restrict__ xb, unsigned short* __restrict__ wb,
    unsigned short* __restrict__ cb) {
  const size_t g = (size_t)blockIdx.x * 256 + threadIdx.x;
  const size_t NXG = (size_t)M_ROWS * K_DIM / 4;
  const size_t NWG = (size_t)N_COLS * K_DIM / 4;
  const float* src; unsigned short* dst; size_t gg;
  if (g < NXG)            { src = x;    dst = xb; gg = g; }
  else if (g < NXG + NWG) { src = wgt;  dst = wb; gg = g - NXG; }
  else                    { src = cent; dst = cb; gg = g - NXG - NWG; }
  const float4 v = *(const float4*)&src[gg * 4];
  ushort4 o;
  o.x = f2bf(v.x); o.y = f2bf(v.y); o.z = f2bf(v.z); o.w = f2bf(v.w);
  *(ushort4*)&dst[gg * 4] = o;
}

// ---------------- routing via MFMA: cluster-active 64-bit mask ----------------
__global__ __launch_bounds__(64) void routing_mfma_kernel(
    const unsigned short* __restrict__ xb, const unsigned short* __restrict__ cb,
    unsigned long long* __restrict__ mask) {
  __shared__ unsigned short Xl[64 * 32];
  __shared__ unsigned short Cl[64 * 32];
  const int t = threadIdx.x;
  const int lr = t & 15;
  const int lk = (t >> 4) * 8;
  const int row0 = blockIdx.x * 64;

  f32x4 acc[4][4];
  #pragma unroll
  for (int i = 0; i < 4; ++i)
    #pragma unroll
    for (int j = 0; j < 4; ++j) acc[i][j] = {0.f, 0.f, 0.f, 0.f};

  for (int kt = 0; kt < K_DIM / 32; ++kt) {
    #pragma unroll
    for (int it = 0; it < 4; ++it) {
      const int tt = it * 64 + t;
      const int row = tt >> 2;
      const int kc = (tt & 3) * 8;
      const unsigned short* gx = xb + (size_t)(row0 + row) * K_DIM + kt * 32 + kc;
      const unsigned short* gc = cb + (size_t)row * K_DIM + kt * 32 + kc;
      char* lx = (char*)Xl + it * 1024;
      char* lc = (char*)Cl + it * 1024;
      __builtin_amdgcn_global_load_lds((const __attribute__((address_space(1))) void*)gx,
                                       (__attribute__((address_space(3))) void*)lx, 16, 0, 0);
      __builtin_amdgcn_global_load_lds((const __attribute__((address_space(1))) void*)gc,
                                       (__attribute__((address_space(3))) void*)lc, 16, 0, 0);
    }
    __syncthreads();

    bf16x8 af[4], cf[4];
    #pragma unroll
    for (int mi = 0; mi < 4; ++mi)
      af[mi] = *(const bf16x8*)&Xl[(mi * 16 + lr) * 32 + lk];
    #pragma unroll
    for (int ni = 0; ni < 4; ++ni)
      cf[ni] = *(const bf16x8*)&Cl[(ni * 16 + lr) * 32 + lk];
    #pragma unroll
    for (int mi = 0; mi < 4; ++mi)
      #pragma unroll
      for (int ni = 0; ni < 4; ++ni)
        acc[mi][ni] = __builtin_amdgcn_mfma_f32_16x16x32_bf16(af[mi], cf[ni], acc[mi][ni], 0, 0, 0);
    __syncthreads();
  }

  bool colflag[4] = {false, false, false, false};
  #pragma unroll
  for (int mi = 0; mi < 4; ++mi) {
    #pragma unroll
    for (int j = 0; j < 4; ++j) {
      const float v0 = acc[mi][0][j], v1 = acc[mi][1][j],
                  v2 = acc[mi][2][j], v3 = acc[mi][3][j];
      float m = fmaxf(fmaxf(v0, v1), fmaxf(v2, v3));
      #pragma unroll
      for (int off = 8; off >= 1; off >>= 1) m = fmaxf(m, __shfl_xor(m, off));
      float S = expf(v0 - m) + expf(v1 - m) + expf(v2 - m) + expf(v3 - m);
      #pragma unroll
      for (int off = 8; off >= 1; off >>= 1) S += __shfl_xor(S, off);
      const float thr = logf(1e-4f * S);
      colflag[0] |= (v0 - m) > thr;
      colflag[1] |= (v1 - m) > thr;
      colflag[2] |= (v2 - m) > thr;
      colflag[3] |= (v3 - m) > thr;
    }
  }
  unsigned long long bits = 0;
  #pragma unroll
  for (int ni = 0; ni < 4; ++ni) {
    unsigned long long u = __ballot(colflag[ni]);
    u |= u >> 32; u |= u >> 16;
    bits |= (u & 0xFFFFull) << (ni * 16);
  }
  if (t == 0) atomicOr(mask, bits);
}

// ---------------- 256x256 8-phase bf16 MFMA GEMM (T1+T2+T3+T4+T5) ----------------
// out[m][n] = sum_k x[m][k]*W[n][k] (+bias) if cluster_active[assign[n]] else 0
//
// LDS: [dbuf][op A=0/B=1][half][128x64 bf16], swizzled: element (row,chunk8)
// stored at slot row*8 + (chunk ^ (row&7))  -> each ds_read_b128 spreads
// 8 lanes per 4-bank group (minimal). gload_lds dest linear; source chunk
// pre-swizzled with the same involution (both-sides rule).
// Wave w: wm=w&1 (rows mi*32+wm*16+lr), wn=w>>1 (cols ni*64+wn*16+lr).
// Phase (qm,qn) reads A-half qm, B-half qn only -> staggered slot freeing.
__global__ __launch_bounds__(512, 1) void gemm_kernel(
    const unsigned short* __restrict__ xb, const unsigned short* __restrict__ wb,
    const float* __restrict__ bias, const int* __restrict__ assign,
    const unsigned long long* __restrict__ maskp,
    float* __restrict__ out) {
  __shared__ unsigned short lds[2][2][2][128 * 64];   // 128 KB

  const int t = threadIdx.x;
  const int l = t & 63;
  const int w = t >> 6;          // 0..7
  const int wm = w & 1;
  const int wn = w >> 1;         // 0..3
  const int lr = l & 15;
  const int hi4 = l >> 4;        // 0..3

  const int bid = blockIdx.x;
  const int swz = (bid & 7) * (gridDim.x >> 3) + (bid >> 3);   // 512 % 8 == 0
  const int bm = swz >> 4, bn = swz & 15;                      // 32 x 16 tiles
  const int m0 = bm * 256, n0 = bn * 256;

  f32x4 acc[8][4];
  #pragma unroll
  for (int i = 0; i < 8; ++i)
    #pragma unroll
    for (int j = 0; j < 4; ++j) acc[i][j] = {0.f, 0.f, 0.f, 0.f};

  bf16x8 af[4][2];       // current A quad: 4 mi x 2 kk
  bf16x8 bf[2][2][2];    // [qn][ni][kk], both qn kept live

// stage one half-tile (2 gload_lds/thread). Dest linear (slot p = j*512+t),
// source chunk = (p&7) ^ (row&7)  [involution, matches read swizzle].
#define STAGE(OP, D, H, KT) do {                                               \
    const unsigned short* _src = (OP) ? wb : xb;                               \
    const int _rb = ((OP) ? n0 : m0) + (H) * 128;                              \
    _Pragma("unroll")                                                          \
    for (int _j = 0; _j < 2; ++_j) {                                           \
      const int _p = _j * 512 + t;                                             \
      const int _row = _p >> 3;                                                \
      const int _ch = (_p & 7) ^ (_row & 7);                                   \
      const unsigned short* _g = _src + (size_t)(_rb + _row) * K_DIM           \
                                 + (KT) * 64 + _ch * 8;                        \
      char* _d = (char*)&lds[D][OP][H][0] + _j * 8192 + w * 1024;              \
      __builtin_amdgcn_global_load_lds(                                        \
          (const __attribute__((address_space(1))) void*)_g,                   \
          (__attribute__((address_space(3))) void*)_d, 16, 0, 0);              \
    }                                                                          \
  } while (0)

#define LDA(D, QM) do {                                                        \
    _Pragma("unroll")                                                          \
    for (int _mi = 0; _mi < 4; ++_mi) {                                        \
      const int _row = _mi * 32 + wm * 16 + lr;                                \
      _Pragma("unroll")                                                        \
      for (int _kk = 0; _kk < 2; ++_kk) {                                      \
        const int _ch = (_kk * 4 + hi4) ^ (_row & 7);                          \
        af[_mi][_kk] = *(const bf16x8*)&lds[D][0][QM][_row * 64 + _ch * 8];    \
      }                                                                        \
    }                                                                          \
  } while (0)

#define LDB(D, QN) do {                                                        \
    _Pragma("unroll")                                                          \
    for (int _ni = 0; _ni < 2; ++_ni) {                                        \
      const int _row = _ni * 64 + wn * 16 + lr;                                \
      _Pragma("unroll")                                                        \
      for (int _kk = 0; _kk < 2; ++_kk) {                                      \
        const int _ch = (_kk * 4 + hi4) ^ (_row & 7);                          \
        bf[QN][_ni][_kk] = *(const bf16x8*)&lds[D][1][QN][_row * 64 + _ch * 8];\
      }                                                                        \
    }                                                                          \
  } while (0)

#define MFMAQ(QM, QN) do {                                                     \
    __builtin_amdgcn_s_setprio(1);                                             \
    _Pragma("unroll")                                                          \
    for (int _kk = 0; _kk < 2; ++_kk)                                          \
      _Pragma("unroll")                                                        \
      for (int _mi = 0; _mi < 4; ++_mi)                                        \
        _Pragma("unroll")                                                      \
        for (int _ni = 0; _ni < 2; ++_ni)                                      \
          acc[(QM)*4 + _mi][(QN)*2 + _ni] =                                    \
              __builtin_amdgcn_mfma_f32_16x16x32_bf16(                         \
                  af[_mi][_kk], bf[QN][_ni][_kk],                              \
                  acc[(QM)*4 + _mi][(QN)*2 + _ni], 0, 0, 0);                   \
    __builtin_amdgcn_s_setprio(0);                                             \
  } while (0)

#define WAITV(N) asm volatile("s_waitcnt vmcnt(" #N ")" ::: "memory")
#define BAR() do { asm volatile("" ::: "memory"); __builtin_amdgcn_s_barrier(); } while (0)

  // ---- prologue: stage in steady-state issue order, then counted wait ----
  STAGE(0, 0, 0, 0);   // A0(0)
  STAGE(1, 0, 0, 0);   // B0(0)
  STAGE(0, 0, 1, 0);   // A1(0)
  STAGE(1, 0, 1, 0);   // B1(0)
  STAGE(0, 1, 0, 1);   // A0(1) -> dbuf1
  STAGE(1, 1, 0, 1);   // B0(1)
  WAITV(4);            // tile0's 4 halves landed; A0(1),B0(1) in flight
  BAR();

  // ---- main loop: iterations 0..6 (tiles 2i, 2i+1), full staging ----
  for (int i = 0; i < 7; ++i) {
    const int k1 = 2 * i + 1, k2 = 2 * i + 2, k3 = 2 * i + 3;
    // P1
    LDA(0, 0); LDB(0, 0); STAGE(0, 1, 1, k1); MFMAQ(0, 0); BAR();
    // P2
    LDB(0, 1);            STAGE(1, 1, 1, k1); MFMAQ(0, 1); BAR();
    // P3
    LDA(0, 1);            STAGE(0, 0, 0, k2); MFMAQ(1, 0); BAR();
    // P4
                          STAGE(1, 0, 0, k2); MFMAQ(1, 1); WAITV(8); BAR();
    // P5
    LDA(1, 0); LDB(1, 0); STAGE(0, 0, 1, k2); MFMAQ(0, 0); WAITV(6); BAR();
    // P6
    LDB(1, 1);            STAGE(1, 0, 1, k2); MFMAQ(0, 1); BAR();
    // P7
    LDA(1, 1);            STAGE(0, 1, 0, k3); MFMAQ(1, 0); BAR();
    // P8
                          STAGE(1, 1, 0, k3); MFMAQ(1, 1); WAITV(4); BAR();
  }

  // ---- tail: iteration 7 (tiles 14,15), no further staging ----
  // P1
  LDA(0, 0); LDB(0, 0); STAGE(0, 1, 1, 15); MFMAQ(0, 0); BAR();
  // P2
  LDB(0, 1);            STAGE(1, 1, 1, 15); MFMAQ(0, 1); BAR();
  // P3
  LDA(0, 1);                                MFMAQ(1, 0); BAR();
  // P4  (outstanding: A1(15),B1(15)=4; older A0(15),B0(15) land)
                                            MFMAQ(1, 1); WAITV(4); BAR();
  // P5  (drain: B1(15) lands)
  LDA(1, 0); LDB(1, 0);                     MFMAQ(0, 0); WAITV(0); BAR();
  // P6
  LDB(1, 1);                                MFMAQ(0, 1); BAR();
  // P7
  LDA(1, 1);                                MFMAQ(1, 0); BAR();
  // P8
                                            MFMAQ(1, 1);

  // ---- epilogue: fused mask + bias ----
  const unsigned long long mask = *maskp;
  #pragma unroll
  for (int ni = 0; ni < 4; ++ni) {
    const int col = n0 + ni * 64 + wn * 16 + lr;
    const int a = assign[col];
    const bool act = (mask >> a) & 1ull;
    const float bv = bias[col];
    #pragma unroll
    for (int mi = 0; mi < 8; ++mi) {
      const int rowb = m0 + mi * 32 + wm * 16 + hi4 * 4;
      #pragma unroll
      for (int j = 0; j < 4; ++j) {
        out[(size_t)(rowb + j) * N_COLS + col] = act ? (acc[mi][ni][j] + bv) : 0.0f;
      }
    }
  }
#undef STAGE
#undef LDA
#undef LDB
#undef MFMAQ
#undef WAITV
#undef BAR
}

extern "C" void kernel_launch(void* const* d_in, const int* in_sizes, int n_in,
                              void* d_out, int out_size, void* d_ws, size_t ws_size,
                              hipStream_t stream) {
  const float* x    = (const float*)d_in[0];
  const float* wgt  = (const float*)d_in[1];
  const float* bias = (const float*)d_in[2];
  const float* cent = (const float*)d_in[3];
  const int* assign = (const int*)d_in[4];
  float* out = (float*)d_out;

  unsigned long long* mask = (unsigned long long*)d_ws;
  unsigned short* xb = (unsigned short*)((char*)d_ws + 256);
  unsigned short* wb = xb + (size_t)M_ROWS * K_DIM;
  unsigned short* cb = wb + (size_t)N_COLS * K_DIM;

  hipMemsetAsync(d_ws, 0, 8, stream);
  const int ngroups = (M_ROWS * K_DIM + N_COLS * K_DIM + N_CLUS * K_DIM) / 4;
  hipLaunchKernelGGL(convert_kernel, dim3(ngroups / 256), dim3(256), 0, stream,
                     x, wgt, cent, xb, wb, cb);
  hipLaunchKernelGGL(routing_mfma_kernel, dim3(M_ROWS / 64), dim3(64), 0, stream,
                     xb, cb, mask);
  hipLaunchKernelGGL(gemm_kernel, dim3((M_ROWS / 256) * (N_COLS / 256)), dim3(512), 0, stream,
                     xb, wb, bias, assign, mask, out);
}

// Round 5
// 107.208 us; speedup vs baseline: 2.2884x; 1.0960x over previous
//
#include <hip/hip_runtime.h>
#include <hip/hip_bf16.h>
#include <stdint.h>

#define M_ROWS 8192
#define K_DIM  1024
#define N_COLS 4096
#define N_CLUS 64

typedef short bf16x8 __attribute__((ext_vector_type(8)));
typedef float f32x4  __attribute__((ext_vector_type(4)));

__device__ __forceinline__ unsigned short f2bf(float f) {
  unsigned int u = __float_as_uint(f);
  unsigned int r = (u + 0x7FFFu + ((u >> 16) & 1u)) >> 16;
  return (unsigned short)r;
}

// ---------------- fp32 -> bf16 conversion (x, W, centroids) + mask init ----------------
__global__ __launch_bounds__(256) void convert_kernel(
    const float* __restrict__ x, const float* __restrict__ wgt,
    const float* __restrict__ cent,
    unsigned short* __restrict__ xb, unsigned short* __restrict__ wb,
    unsigned short* __restrict__ cb,
    unsigned long long* __restrict__ mask) {
  const size_t g = (size_t)blockIdx.x * 256 + threadIdx.x;
  if (g == 0) *mask = 0ull;   // stream-ordered before routing's atomicOr
  const size_t NXG = (size_t)M_ROWS * K_DIM / 4;
  const size_t NWG = (size_t)N_COLS * K_DIM / 4;
  const float* src; unsigned short* dst; size_t gg;
  if (g < NXG)            { src = x;    dst = xb; gg = g; }
  else if (g < NXG + NWG) { src = wgt;  dst = wb; gg = g - NXG; }
  else                    { src = cent; dst = cb; gg = g - NXG - NWG; }
  const float4 v = *(const float4*)&src[gg * 4];
  ushort4 o;
  o.x = f2bf(v.x); o.y = f2bf(v.y); o.z = f2bf(v.z); o.w = f2bf(v.w);
  *(ushort4*)&dst[gg * 4] = o;
}

// ---------------- routing via MFMA: cluster-active 64-bit mask ----------------
// 256 blocks x 1 wave x 32 rows (fills all CUs). logits = x @ C^T, bf16 MFMA.
__global__ __launch_bounds__(64) void routing_mfma_kernel(
    const unsigned short* __restrict__ xb, const unsigned short* __restrict__ cb,
    unsigned long long* __restrict__ mask) {
  __shared__ unsigned short Xl[32 * 32];   // 2 KB
  __shared__ unsigned short Cl[64 * 32];   // 4 KB
  const int t = threadIdx.x;
  const int lr = t & 15;
  const int lk = (t >> 4) * 8;
  const int row0 = blockIdx.x * 32;

  f32x4 acc[2][4];
  #pragma unroll
  for (int i = 0; i < 2; ++i)
    #pragma unroll
    for (int j = 0; j < 4; ++j) acc[i][j] = {0.f, 0.f, 0.f, 0.f};

  for (int kt = 0; kt < K_DIM / 32; ++kt) {
    #pragma unroll
    for (int it = 0; it < 2; ++it) {       // X: 32 rows x 32 k
      const int tt = it * 64 + t;
      const int row = tt >> 2;
      const int kc = (tt & 3) * 8;
      const unsigned short* gx = xb + (size_t)(row0 + row) * K_DIM + kt * 32 + kc;
      char* lx = (char*)Xl + it * 1024;
      __builtin_amdgcn_global_load_lds((const __attribute__((address_space(1))) void*)gx,
                                       (__attribute__((address_space(3))) void*)lx, 16, 0, 0);
    }
    #pragma unroll
    for (int it = 0; it < 4; ++it) {       // C: 64 rows x 32 k
      const int tt = it * 64 + t;
      const int row = tt >> 2;
      const int kc = (tt & 3) * 8;
      const unsigned short* gc = cb + (size_t)row * K_DIM + kt * 32 + kc;
      char* lc = (char*)Cl + it * 1024;
      __builtin_amdgcn_global_load_lds((const __attribute__((address_space(1))) void*)gc,
                                       (__attribute__((address_space(3))) void*)lc, 16, 0, 0);
    }
    __syncthreads();

    bf16x8 af[2], cf[4];
    #pragma unroll
    for (int mi = 0; mi < 2; ++mi)
      af[mi] = *(const bf16x8*)&Xl[(mi * 16 + lr) * 32 + lk];
    #pragma unroll
    for (int ni = 0; ni < 4; ++ni)
      cf[ni] = *(const bf16x8*)&Cl[(ni * 16 + lr) * 32 + lk];
    #pragma unroll
    for (int mi = 0; mi < 2; ++mi)
      #pragma unroll
      for (int ni = 0; ni < 4; ++ni)
        acc[mi][ni] = __builtin_amdgcn_mfma_f32_16x16x32_bf16(af[mi], cf[ni], acc[mi][ni], 0, 0, 0);
    __syncthreads();
  }

  bool colflag[4] = {false, false, false, false};
  #pragma unroll
  for (int mi = 0; mi < 2; ++mi) {
    #pragma unroll
    for (int j = 0; j < 4; ++j) {
      const float v0 = acc[mi][0][j], v1 = acc[mi][1][j],
                  v2 = acc[mi][2][j], v3 = acc[mi][3][j];
      float m = fmaxf(fmaxf(v0, v1), fmaxf(v2, v3));
      #pragma unroll
      for (int off = 8; off >= 1; off >>= 1) m = fmaxf(m, __shfl_xor(m, off));
      float S = expf(v0 - m) + expf(v1 - m) + expf(v2 - m) + expf(v3 - m);
      #pragma unroll
      for (int off = 8; off >= 1; off >>= 1) S += __shfl_xor(S, off);
      const float thr = logf(1e-4f * S);
      colflag[0] |= (v0 - m) > thr;
      colflag[1] |= (v1 - m) > thr;
      colflag[2] |= (v2 - m) > thr;
      colflag[3] |= (v3 - m) > thr;
    }
  }
  unsigned long long bits = 0;
  #pragma unroll
  for (int ni = 0; ni < 4; ++ni) {
    unsigned long long u = __ballot(colflag[ni]);
    u |= u >> 32; u |= u >> 16;
    bits |= (u & 0xFFFFull) << (ni * 16);
  }
  if (t == 0) atomicOr(mask, bits);
}

// ---------------- 256x256 8-phase bf16 MFMA GEMM (T1+T2+T3+T4+T5) ----------------
// Minimal-drain wait schedule (derived from per-wave outstanding-queue trace):
// steady-state waits P1:vmcnt(6) P4:(8) P5:(6) P8:(8); 8 loads in flight at P1.
__global__ __launch_bounds__(512, 1) void gemm_kernel(
    const unsigned short* __restrict__ xb, const unsigned short* __restrict__ wb,
    const float* __restrict__ bias, const int* __restrict__ assign,
    const unsigned long long* __restrict__ maskp,
    float* __restrict__ out) {
  __shared__ unsigned short lds[2][2][2][128 * 64];   // 128 KB

  const int t = threadIdx.x;
  const int l = t & 63;
  const int w = t >> 6;          // 0..7
  const int wm = w & 1;
  const int wn = w >> 1;         // 0..3
  const int lr = l & 15;
  const int hi4 = l >> 4;        // 0..3

  const int bid = blockIdx.x;
  const int swz = (bid & 7) * (gridDim.x >> 3) + (bid >> 3);   // 512 % 8 == 0
  const int bm = swz >> 4, bn = swz & 15;                      // 32 x 16 tiles
  const int m0 = bm * 256, n0 = bn * 256;

  f32x4 acc[8][4];
  #pragma unroll
  for (int i = 0; i < 8; ++i)
    #pragma unroll
    for (int j = 0; j < 4; ++j) acc[i][j] = {0.f, 0.f, 0.f, 0.f};

  bf16x8 af[4][2];       // current A quad: 4 mi x 2 kk
  bf16x8 bf[2][2][2];    // [qn][ni][kk]

#define STAGE(OP, D, H, KT) do {                                               \
    const unsigned short* _src = (OP) ? wb : xb;                               \
    const int _rb = ((OP) ? n0 : m0) + (H) * 128;                              \
    _Pragma("unroll")                                                          \
    for (int _j = 0; _j < 2; ++_j) {                                           \
      const int _p = _j * 512 + t;                                             \
      const int _row = _p >> 3;                                                \
      const int _ch = (_p & 7) ^ (_row & 7);                                   \
      const unsigned short* _g = _src + (size_t)(_rb + _row) * K_DIM           \
                                 + (KT) * 64 + _ch * 8;                        \
      char* _d = (char*)&lds[D][OP][H][0] + _j * 8192 + w * 1024;              \
      __builtin_amdgcn_global_load_lds(                                        \
          (const __attribute__((address_space(1))) void*)_g,                   \
          (__attribute__((address_space(3))) void*)_d, 16, 0, 0);              \
    }                                                                          \
  } while (0)

#define LDA(D, QM) do {                                                        \
    _Pragma("unroll")                                                          \
    for (int _mi = 0; _mi < 4; ++_mi) {                                        \
      const int _row = _mi * 32 + wm * 16 + lr;                                \
      _Pragma("unroll")                                                        \
      for (int _kk = 0; _kk < 2; ++_kk) {                                      \
        const int _ch = (_kk * 4 + hi4) ^ (_row & 7);                          \
        af[_mi][_kk] = *(const bf16x8*)&lds[D][0][QM][_row * 64 + _ch * 8];    \
      }                                                                        \
    }                                                                          \
  } while (0)

#define LDB(D, QN) do {                                                        \
    _Pragma("unroll")                                                          \
    for (int _ni = 0; _ni < 2; ++_ni) {                                        \
      const int _row = _ni * 64 + wn * 16 + lr;                                \
      _Pragma("unroll")                                                        \
      for (int _kk = 0; _kk < 2; ++_kk) {                                      \
        const int _ch = (_kk * 4 + hi4) ^ (_row & 7);                          \
        bf[QN][_ni][_kk] = *(const bf16x8*)&lds[D][1][QN][_row * 64 + _ch * 8];\
      }                                                                        \
    }                                                                          \
  } while (0)

#define MFMAQ(QM, QN) do {                                                     \
    __builtin_amdgcn_s_setprio(1);                                             \
    _Pragma("unroll")                                                          \
    for (int _kk = 0; _kk < 2; ++_kk)                                          \
      _Pragma("unroll")                                                        \
      for (int _mi = 0; _mi < 4; ++_mi)                                        \
        _Pragma("unroll")                                                      \
        for (int _ni = 0; _ni < 2; ++_ni)                                      \
          acc[(QM)*4 + _mi][(QN)*2 + _ni] =                                    \
              __builtin_amdgcn_mfma_f32_16x16x32_bf16(                         \
                  af[_mi][_kk], bf[QN][_ni][_kk],                              \
                  acc[(QM)*4 + _mi][(QN)*2 + _ni], 0, 0, 0);                   \
    __builtin_amdgcn_s_setprio(0);                                             \
  } while (0)

#define WAITV(N) asm volatile("s_waitcnt vmcnt(" #N ")" ::: "memory")
#define BAR() do { asm volatile("" ::: "memory"); __builtin_amdgcn_s_barrier(); } while (0)

  // ---- prologue ----
  STAGE(0, 0, 0, 0);   // A0(0)
  STAGE(1, 0, 0, 0);   // B0(0)
  STAGE(0, 0, 1, 0);   // A1(0)
  STAGE(1, 0, 1, 0);   // B1(0)
  STAGE(0, 1, 0, 1);   // A0(1)
  STAGE(1, 1, 0, 1);   // B0(1)
  WAITV(8);            // A0(0),B0(0) landed; 8 in flight
  BAR();

  // ---- main loop: iterations 0..6 (tiles 2i, 2i+1) ----
  for (int i = 0; i < 7; ++i) {
    const int k1 = 2 * i + 1, k2 = 2 * i + 2, k3 = 2 * i + 3;
    // P1: drains A1(2i),B1(2i) for P2/P3
    LDA(0, 0); LDB(0, 0); STAGE(0, 1, 1, k1); MFMAQ(0, 0); WAITV(6); BAR();
    // P2
    LDB(0, 1);            STAGE(1, 1, 1, k1); MFMAQ(0, 1); BAR();
    // P3
    LDA(0, 1);            STAGE(0, 0, 0, k2); MFMAQ(1, 0); BAR();
    // P4: drains A0(k1),B0(k1) for P5
                          STAGE(1, 0, 0, k2); MFMAQ(1, 1); WAITV(8); BAR();
    // P5: drains A1(k1),B1(k1) for P6/P7
    LDA(1, 0); LDB(1, 0); STAGE(0, 0, 1, k2); MFMAQ(0, 0); WAITV(6); BAR();
    // P6
    LDB(1, 1);            STAGE(1, 0, 1, k2); MFMAQ(0, 1); BAR();
    // P7
    LDA(1, 1);            STAGE(0, 1, 0, k3); MFMAQ(1, 0); BAR();
    // P8: drains A0(k2),B0(k2) for next-P1
                          STAGE(1, 1, 0, k3); MFMAQ(1, 1); WAITV(8); BAR();
  }

  // ---- tail: iteration 7 (tiles 14,15) ----
  // T1: drains A1(14),B1(14)
  LDA(0, 0); LDB(0, 0); STAGE(0, 1, 1, 15); MFMAQ(0, 0); WAITV(6); BAR();
  // T2
  LDB(0, 1);            STAGE(1, 1, 1, 15); MFMAQ(0, 1); BAR();
  // T3
  LDA(0, 1);                                MFMAQ(1, 0); BAR();
  // T4: [A0(15),B0(15),A1(15),B1(15)]=8 -> drains A0(15),B0(15)
                                            MFMAQ(1, 1); WAITV(4); BAR();
  // T5: drains A1(15),B1(15)
  LDA(1, 0); LDB(1, 0);                     MFMAQ(0, 0); WAITV(0); BAR();
  // T6
  LDB(1, 1);                                MFMAQ(0, 1); BAR();
  // T7
  LDA(1, 1);                                MFMAQ(1, 0); BAR();
  // T8
                                            MFMAQ(1, 1);

  // ---- epilogue: fused mask + bias ----
  const unsigned long long mask = *maskp;
  #pragma unroll
  for (int ni = 0; ni < 4; ++ni) {
    const int col = n0 + ni * 64 + wn * 16 + lr;
    const int a = assign[col];
    const bool act = (mask >> a) & 1ull;
    const float bv = bias[col];
    #pragma unroll
    for (int mi = 0; mi < 8; ++mi) {
      const int rowb = m0 + mi * 32 + wm * 16 + hi4 * 4;
      #pragma unroll
      for (int j = 0; j < 4; ++j) {
        out[(size_t)(rowb + j) * N_COLS + col] = act ? (acc[mi][ni][j] + bv) : 0.0f;
      }
    }
  }
#undef STAGE
#undef LDA
#undef LDB
#undef MFMAQ
#undef WAITV
#undef BAR
}

extern "C" void kernel_launch(void* const* d_in, const int* in_sizes, int n_in,
                              void* d_out, int out_size, void* d_ws, size_t ws_size,
                              hipStream_t stream) {
  const float* x    = (const float*)d_in[0];
  const float* wgt  = (const float*)d_in[1];
  const float* bias = (const float*)d_in[2];
  const float* cent = (const float*)d_in[3];
  const int* assign = (const int*)d_in[4];
  float* out = (float*)d_out;

  unsigned long long* mask = (unsigned long long*)d_ws;
  unsigned short* xb = (unsigned short*)((char*)d_ws + 256);
  unsigned short* wb = xb + (size_t)M_ROWS * K_DIM;
  unsigned short* cb = wb + (size_t)N_COLS * K_DIM;

  const int ngroups = (M_ROWS * K_DIM + N_COLS * K_DIM + N_CLUS * K_DIM) / 4;
  hipLaunchKernelGGL(convert_kernel, dim3(ngroups / 256), dim3(256), 0, stream,
                     x, wgt, cent, xb, wb, cb, mask);
  hipLaunchKernelGGL(routing_mfma_kernel, dim3(M_ROWS / 32), dim3(64), 0, stream,
                     xb, cb, mask);
  hipLaunchKernelGGL(gemm_kernel, dim3((M_ROWS / 256) * (N_COLS / 256)), dim3(512), 0, stream,
                     xb, wb, bias, assign, mask, out);
}